// Round 2
// baseline (738.467 us; speedup 1.0000x reference)
//
#include <hip/hip_runtime.h>
#include <hip/hip_bf16.h>

typedef __attribute__((ext_vector_type(8))) short short8;
typedef __attribute__((ext_vector_type(4))) float f32x4;

__device__ inline float b2f(unsigned short u) {
    union { unsigned int i; float f; } c; c.i = ((unsigned int)u) << 16; return c.f;
}
__device__ inline unsigned short f2b(float f) {
    __hip_bfloat16 h = __float2bfloat16(f);
    return *reinterpret_cast<unsigned short*>(&h);
}

// fp32 -> bf16 conversion, 4 elems/thread (float4 in, 8B out)
__global__ __launch_bounds__(256) void cvt_f32_bf16(
    const float* __restrict__ src, unsigned short* __restrict__ dst, int n4)
{
    int i = blockIdx.x * 256 + threadIdx.x;
    if (i >= n4) return;
    float4 v = ((const float4*)src)[i];
    union { unsigned short u[4]; unsigned long long ll; } p;
    p.u[0] = f2b(v.x); p.u[1] = f2b(v.y); p.u[2] = f2b(v.z); p.u[3] = f2b(v.w);
    ((unsigned long long*)dst)[i] = p.ll;
}

// C[M,N] = scale * A[M,K] @ B + bias   (A,B bf16; bias fp32; C bf16 or fp32)
//  TRANSB=false: B given as Bt[N,K] row-major (QK^T case)
//  TRANSB=true : B given as B[K,N] row-major (weights / V) -> transpose-staged
//  CAUSAL      : skip blocks with bn > bm
//  KCAUSAL     : K-loop limited to (bm+1)*128 (PV with zero-padded P tiles)
//  OUTF32      : C written as fp32 (final output), else bf16
template<bool TRANSB, bool CAUSAL, bool KCAUSAL, bool OUTF32>
__global__ __launch_bounds__(256) void gemm128(
    const unsigned short* __restrict__ A, const unsigned short* __restrict__ B,
    const float* __restrict__ bias, void* __restrict__ Cv,
    int M, int N, int K, long sA, long sB, long sC, float scale)
{
    const int bm = blockIdx.x, bn = blockIdx.y;
    if (CAUSAL && bn > bm) return;
    A += (long)blockIdx.z * sA;
    B += (long)blockIdx.z * sB;
    const int m0 = bm * 128, n0 = bn * 128;

    __shared__ __attribute__((aligned(16))) unsigned short As[128 * 32];
    __shared__ __attribute__((aligned(16))) unsigned short Bs[128 * 32];

    const int t = threadIdx.x;
    const int lane = t & 63;
    const int w = t >> 6;
    const int wr = w >> 1, wc = w & 1;          // wave's 64x64 quadrant
    const int lrow = lane & 15, quad = lane >> 4;

    f32x4 acc[4][4];
    #pragma unroll
    for (int i = 0; i < 4; i++)
        #pragma unroll
        for (int j = 0; j < 4; j++)
            acc[i][j] = (f32x4){0.f, 0.f, 0.f, 0.f};

    const int Keff = KCAUSAL ? (((bm + 1) * 128 < K) ? (bm + 1) * 128 : K) : K;

    const int segA = t & 3, rA = t >> 2;        // A staging: 4 x 8-elem segs per row
    const int kkB = t >> 4, nsB = t & 15;       // TRANSB staging

    for (int k0 = 0; k0 < Keff; k0 += 32) {
        #pragma unroll
        for (int rr = rA; rr < 128; rr += 64)
            *(short8*)&As[rr * 32 + segA * 8] =
                *(const short8*)(A + (long)(m0 + rr) * K + k0 + segA * 8);
        if (!TRANSB) {
            #pragma unroll
            for (int rr = rA; rr < 128; rr += 64)
                *(short8*)&Bs[rr * 32 + segA * 8] =
                    *(const short8*)(B + (long)(n0 + rr) * K + k0 + segA * 8);
        } else {
            #pragma unroll
            for (int k2 = kkB; k2 < 32; k2 += 16) {
                short8 v = *(const short8*)(B + (long)(k0 + k2) * N + n0 + nsB * 8);
                #pragma unroll
                for (int i = 0; i < 8; i++)
                    Bs[(nsB * 8 + i) * 32 + k2] = (unsigned short)v[i];
            }
        }
        __syncthreads();

        short8 af[4], bfr[4];
        #pragma unroll
        for (int mi = 0; mi < 4; mi++)
            af[mi] = *(const short8*)&As[(wr * 64 + mi * 16 + lrow) * 32 + quad * 8];
        #pragma unroll
        for (int ni = 0; ni < 4; ni++)
            bfr[ni] = *(const short8*)&Bs[(wc * 64 + ni * 16 + lrow) * 32 + quad * 8];
        #pragma unroll
        for (int mi = 0; mi < 4; mi++)
            #pragma unroll
            for (int ni = 0; ni < 4; ni++)
                acc[mi][ni] = __builtin_amdgcn_mfma_f32_16x16x32_bf16(
                    af[mi], bfr[ni], acc[mi][ni], 0, 0, 0);
        __syncthreads();
    }

    // epilogue: C/D layout col = lane&15, row = quad*4 + reg
    #pragma unroll
    for (int mi = 0; mi < 4; mi++) {
        const int m = m0 + wr * 64 + mi * 16 + quad * 4;
        #pragma unroll
        for (int ni = 0; ni < 4; ni++) {
            const int n = n0 + wc * 64 + ni * 16 + lrow;
            const float bv = bias ? bias[n] : 0.f;
            #pragma unroll
            for (int r = 0; r < 4; r++) {
                const float val = acc[mi][ni][r] * scale + bv;
                if (OUTF32)
                    ((float*)Cv)[(long)blockIdx.z * sC + (long)(m + r) * N + n] = val;
                else
                    ((unsigned short*)Cv)[(long)blockIdx.z * sC + (long)(m + r) * N + n] = f2b(val);
            }
        }
    }
}

// In-place causal row softmax over S [B*N rows, Nseq cols] (bf16).
// Zero-fills columns [i+1, 128-padded) so PV can read whole 128-wide K tiles.
__global__ __launch_bounds__(256) void softmax_causal(unsigned short* S, int Nseq)
{
    const long row = blockIdx.x;
    const int i = (int)(row % Nseq);
    unsigned short* base = S + row * (long)Nseq;
    const int len = i + 1;
    const int t = threadIdx.x;

    __shared__ float smax[4], ssum[4];

    float lmax = -3.0e38f;
    for (int j = t; j < len; j += 256) lmax = fmaxf(lmax, b2f(base[j]));
    #pragma unroll
    for (int off = 32; off > 0; off >>= 1) lmax = fmaxf(lmax, __shfl_xor(lmax, off, 64));
    if ((t & 63) == 0) smax[t >> 6] = lmax;
    __syncthreads();
    const float gmax = fmaxf(fmaxf(smax[0], smax[1]), fmaxf(smax[2], smax[3]));

    float lsum = 0.f;
    for (int j = t; j < len; j += 256) lsum += __expf(b2f(base[j]) - gmax);
    #pragma unroll
    for (int off = 32; off > 0; off >>= 1) lsum += __shfl_xor(lsum, off, 64);
    if ((t & 63) == 0) ssum[t >> 6] = lsum;
    __syncthreads();
    const float inv = 1.0f / (ssum[0] + ssum[1] + ssum[2] + ssum[3]);

    const int padded = ((i >> 7) + 1) << 7;   // round len up to 128 boundary
    for (int j = t; j < padded; j += 256) {
        const float v = (j < len) ? __expf(b2f(base[j]) - gmax) * inv : 0.f;
        base[j] = f2b(v);
    }
}

extern "C" void kernel_launch(void* const* d_in, const int* in_sizes, int n_in,
                              void* d_out, int out_size, void* d_ws, size_t ws_size,
                              hipStream_t stream)
{
    // inputs (fp32): x, mask(ignored - known causal), Wq, bq, Wk, bk, Wv, bv, Wo, bo
    const float* x  = (const float*)d_in[0];
    const float* Wq = (const float*)d_in[2];
    const float* bq = (const float*)d_in[3];
    const float* Wk = (const float*)d_in[4];
    const float* bk = (const float*)d_in[5];
    const float* Wv = (const float*)d_in[6];
    const float* bv = (const float*)d_in[7];
    const float* Wo = (const float*)d_in[8];
    const float* bo = (const float*)d_in[9];

    unsigned short* ws = (unsigned short*)d_ws;
    const long XSZ = 8192L * 1024;            // 8,388,608
    const long WSZ = 1024L * 1024;            // 1,048,576
    unsigned short* xb  = ws;                 // [8192,1024] bf16  (reused for attn-out later)
    unsigned short* Wqb = ws + XSZ;
    unsigned short* Wkb = Wqb + WSZ;
    unsigned short* Wvb = Wkb + WSZ;
    unsigned short* Wob = Wvb + WSZ;
    unsigned short* Q   = Wob + WSZ;
    unsigned short* Km  = Q + XSZ;
    unsigned short* V   = Km + XSZ;
    unsigned short* S   = V + XSZ;            // 4*2048*2048 elems (S -> P in place)
    unsigned short* Aat = xb;                 // alias: x dead after V projection
    // total: 5*XSZ + 4*WSZ + 16.7M = ~104 MiB

    const dim3 blk(256);

    // fp32 -> bf16 conversions
    cvt_f32_bf16<<<dim3(8192), blk, 0, stream>>>(x,  xb,  (int)(XSZ / 4));
    cvt_f32_bf16<<<dim3(1024), blk, 0, stream>>>(Wq, Wqb, (int)(WSZ / 4));
    cvt_f32_bf16<<<dim3(1024), blk, 0, stream>>>(Wk, Wkb, (int)(WSZ / 4));
    cvt_f32_bf16<<<dim3(1024), blk, 0, stream>>>(Wv, Wvb, (int)(WSZ / 4));
    cvt_f32_bf16<<<dim3(1024), blk, 0, stream>>>(Wo, Wob, (int)(WSZ / 4));

    // QKV projections: [8192,1024] @ [1024,1024] + b  (bf16 out)
    gemm128<true,  false, false, false><<<dim3(64, 8, 1), blk, 0, stream>>>(
        xb, Wqb, bq, Q,  8192, 1024, 1024, 0, 0, 0, 1.f);
    gemm128<true,  false, false, false><<<dim3(64, 8, 1), blk, 0, stream>>>(
        xb, Wkb, bk, Km, 8192, 1024, 1024, 0, 0, 0, 1.f);
    gemm128<true,  false, false, false><<<dim3(64, 8, 1), blk, 0, stream>>>(
        xb, Wvb, bv, V,  8192, 1024, 1024, 0, 0, 0, 1.f);

    // S = Q K^T / sqrt(D), causal blocks only (per-batch via grid.z)
    gemm128<false, true,  false, false><<<dim3(16, 16, 4), blk, 0, stream>>>(
        Q, Km, nullptr, S, 2048, 2048, 1024,
        2048L * 1024, 2048L * 1024, 2048L * 2048, 0.03125f);

    // causal softmax rows, in place, zero-padded to 128 boundary
    softmax_causal<<<dim3(4 * 2048), blk, 0, stream>>>(S, 2048);

    // A = P @ V, K-loop truncated at (bm+1)*128  (writes into xb alias)
    gemm128<true,  false, true,  false><<<dim3(16, 8, 4), blk, 0, stream>>>(
        S, V, nullptr, Aat, 2048, 1024, 2048,
        2048L * 2048, 2048L * 1024, 2048L * 1024, 1.f);

    // out = A @ Wo + bo  (fp32 out)
    gemm128<true,  false, false, true ><<<dim3(64, 8, 1), blk, 0, stream>>>(
        Aat, Wob, bo, (float*)d_out, 8192, 1024, 1024, 0, 0, 0, 1.f);
}

// Round 3
// 419.986 us; speedup vs baseline: 1.7583x; 1.7583x over previous
//
#include <hip/hip_runtime.h>
#include <hip/hip_bf16.h>

typedef __attribute__((ext_vector_type(8))) short short8;
typedef __attribute__((ext_vector_type(4))) float f32x4;

__device__ inline float b2f(unsigned short u) {
    union { unsigned int i; float f; } c; c.i = ((unsigned int)u) << 16; return c.f;
}
__device__ inline unsigned short f2b(float f) {
    __hip_bfloat16 h = __float2bfloat16(f);
    return *reinterpret_cast<unsigned short*>(&h);
}

// async global->LDS, 16 B per lane; LDS dest = wave-uniform base + lane*16
__device__ inline void gl_lds16(const unsigned short* g, unsigned short* ldsbase) {
    __builtin_amdgcn_global_load_lds(
        (const __attribute__((address_space(1))) unsigned int*)(g),
        (__attribute__((address_space(3))) unsigned int*)(ldsbase),
        16, 0, 0);
}

// fp32 -> bf16 conversion, 4 elems/thread
__global__ __launch_bounds__(256) void cvt_f32_bf16(
    const float* __restrict__ src, unsigned short* __restrict__ dst, int n4)
{
    int i = blockIdx.x * 256 + threadIdx.x;
    if (i >= n4) return;
    float4 v = ((const float4*)src)[i];
    union { unsigned short u[4]; unsigned long long ll; } p;
    p.u[0] = f2b(v.x); p.u[1] = f2b(v.y); p.u[2] = f2b(v.z); p.u[3] = f2b(v.w);
    ((unsigned long long*)dst)[i] = p.ll;
}

// fp32 [R,C] -> bf16 transposed [C,R], 32x32 LDS tiles
__global__ __launch_bounds__(256) void cvt_transpose(
    const float* __restrict__ src, unsigned short* __restrict__ dst, int R, int C)
{
    __shared__ float tile[32][33];
    const int c0 = blockIdx.x * 32, r0 = blockIdx.y * 32;
    const int tx = threadIdx.x & 31, ty = threadIdx.x >> 5;   // ty 0..7
    #pragma unroll
    for (int i = ty; i < 32; i += 8)
        tile[i][tx] = src[(long)(r0 + i) * C + c0 + tx];
    __syncthreads();
    #pragma unroll
    for (int i = ty; i < 32; i += 8)
        dst[(long)(c0 + i) * R + r0 + tx] = f2b(tile[tx][i]);
}

// C[M,N] = scale * A[M,K] @ Bt^T + bias   (A,Bt bf16; bias fp32)
//  A row stride lda, Bt row stride ldb (Bt is [N,K]).
//  OMODE 0: C bf16, idx z*sC + m*ldc + n
//  OMODE 1: C fp32, idx z*sC + m*ldc + n
//  OMODE 2: C bf16 transposed, idx z*sC + n*ldc + m  (V^T production)
//  CAUSAL : skip blocks bn > bm;  KCAUSAL: K-loop capped at (bm+1)*128
template<bool CAUSAL, bool KCAUSAL, int OMODE>
__global__ __launch_bounds__(256) void gemm128(
    const unsigned short* __restrict__ A, const unsigned short* __restrict__ Bt,
    const float* __restrict__ bias, void* __restrict__ Cv,
    int K, int lda, int ldb, int ldc, long sA, long sB, long sC, float scale)
{
    const int bm = blockIdx.x, bn = blockIdx.y;
    if (CAUSAL && bn > bm) return;
    A  += (long)blockIdx.z * sA;
    Bt += (long)blockIdx.z * sB;
    const int m0 = bm * 128, n0 = bn * 128;

    __shared__ __attribute__((aligned(16))) unsigned short As[128 * 32];
    __shared__ __attribute__((aligned(16))) unsigned short Bs[128 * 32];

    const int t = threadIdx.x, lane = t & 63, w = t >> 6;
    const int wr = w >> 1, wc = w & 1;           // wave's 64x64 quadrant
    const int lrow = lane & 15, quad = lane >> 4;

    f32x4 acc[4][4];
    #pragma unroll
    for (int i = 0; i < 4; i++)
        #pragma unroll
        for (int j = 0; j < 4; j++)
            acc[i][j] = (f32x4){0.f, 0.f, 0.f, 0.f};

    const int Keff = KCAUSAL ? ((bm + 1) * 128 < K ? (bm + 1) * 128 : K) : K;

    // lane's global row/segment for async staging (wave w owns rows [w*32, w*32+32))
    const unsigned short* gA = A  + (long)(m0 + w * 32 + (lane >> 2)) * lda + (lane & 3) * 8;
    const unsigned short* gB = Bt + (long)(n0 + w * 32 + (lane >> 2)) * ldb + (lane & 3) * 8;
    unsigned short* lA0 = &As[(w * 32) * 32];
    unsigned short* lA1 = &As[(w * 32 + 16) * 32];
    unsigned short* lB0 = &Bs[(w * 32) * 32];
    unsigned short* lB1 = &Bs[(w * 32 + 16) * 32];

    for (int k0 = 0; k0 < Keff; k0 += 32) {
        gl_lds16(gA + k0,            lA0);
        gl_lds16(gA + k0 + 16 * lda, lA1);
        gl_lds16(gB + k0,            lB0);
        gl_lds16(gB + k0 + 16 * ldb, lB1);
        __syncthreads();

        short8 af[4], bfr[4];
        #pragma unroll
        for (int mi = 0; mi < 4; mi++)
            af[mi] = *(const short8*)&As[(wr * 64 + mi * 16 + lrow) * 32 + quad * 8];
        #pragma unroll
        for (int ni = 0; ni < 4; ni++)
            bfr[ni] = *(const short8*)&Bs[(wc * 64 + ni * 16 + lrow) * 32 + quad * 8];
        #pragma unroll
        for (int mi = 0; mi < 4; mi++)
            #pragma unroll
            for (int ni = 0; ni < 4; ni++)
                acc[mi][ni] = __builtin_amdgcn_mfma_f32_16x16x32_bf16(
                    af[mi], bfr[ni], acc[mi][ni], 0, 0, 0);
        __syncthreads();
    }

    // epilogue: C/D layout col = lane&15, row = quad*4 + reg
    #pragma unroll
    for (int mi = 0; mi < 4; mi++) {
        const int m = m0 + wr * 64 + mi * 16 + quad * 4;
        #pragma unroll
        for (int ni = 0; ni < 4; ni++) {
            const int n = n0 + wc * 64 + ni * 16 + lrow;
            const float bv = bias ? bias[n] : 0.f;
            #pragma unroll
            for (int r = 0; r < 4; r++) {
                const float val = acc[mi][ni][r] * scale + bv;
                if (OMODE == 1)
                    ((float*)Cv)[(long)blockIdx.z * sC + (long)(m + r) * ldc + n] = val;
                else if (OMODE == 2)
                    ((unsigned short*)Cv)[(long)blockIdx.z * sC + (long)n * ldc + m + r] = f2b(val);
                else
                    ((unsigned short*)Cv)[(long)blockIdx.z * sC + (long)(m + r) * ldc + n] = f2b(val);
            }
        }
    }
}

// In-place causal row softmax over S [B*N rows, Nseq cols] (bf16).
// Zero-fills columns [i+1, 128-padded) so PV can read whole 128-wide K tiles.
__global__ __launch_bounds__(256) void softmax_causal(unsigned short* S, int Nseq)
{
    const long row = blockIdx.x;
    const int i = (int)(row % Nseq);
    unsigned short* base = S + row * (long)Nseq;
    const int len = i + 1;
    const int t = threadIdx.x;

    __shared__ float smax[4], ssum[4];

    float lmax = -3.0e38f;
    for (int j = t; j < len; j += 256) lmax = fmaxf(lmax, b2f(base[j]));
    #pragma unroll
    for (int off = 32; off > 0; off >>= 1) lmax = fmaxf(lmax, __shfl_xor(lmax, off, 64));
    if ((t & 63) == 0) smax[t >> 6] = lmax;
    __syncthreads();
    const float gmax = fmaxf(fmaxf(smax[0], smax[1]), fmaxf(smax[2], smax[3]));

    float lsum = 0.f;
    for (int j = t; j < len; j += 256) lsum += __expf(b2f(base[j]) - gmax);
    #pragma unroll
    for (int off = 32; off > 0; off >>= 1) lsum += __shfl_xor(lsum, off, 64);
    if ((t & 63) == 0) ssum[t >> 6] = lsum;
    __syncthreads();
    const float inv = 1.0f / (ssum[0] + ssum[1] + ssum[2] + ssum[3]);

    const int padded = ((i >> 7) + 1) << 7;
    for (int j = t; j < padded; j += 256) {
        const float v = (j < len) ? __expf(b2f(base[j]) - gmax) * inv : 0.f;
        base[j] = f2b(v);
    }
}

extern "C" void kernel_launch(void* const* d_in, const int* in_sizes, int n_in,
                              void* d_out, int out_size, void* d_ws, size_t ws_size,
                              hipStream_t stream)
{
    // inputs (fp32): x, mask(ignored - known causal), Wq, bq, Wk, bk, Wv, bv, Wo, bo
    const float* x  = (const float*)d_in[0];
    const float* Wq = (const float*)d_in[2];
    const float* bq = (const float*)d_in[3];
    const float* Wk = (const float*)d_in[4];
    const float* bk = (const float*)d_in[5];
    const float* Wv = (const float*)d_in[6];
    const float* bv = (const float*)d_in[7];
    const float* Wo = (const float*)d_in[8];
    const float* bo = (const float*)d_in[9];

    unsigned short* ws = (unsigned short*)d_ws;
    const long XSZ = 8192L * 1024;            // 8,388,608
    const long WSZ = 1024L * 1024;
    unsigned short* xb  = ws;                 // [8192,1024] bf16 (aliased by attn-out later)
    unsigned short* Wqt = ws + XSZ;           // [1024,1024] = Wq^T
    unsigned short* Wkt = Wqt + WSZ;
    unsigned short* Wvt = Wkt + WSZ;
    unsigned short* Wot = Wvt + WSZ;
    unsigned short* Q   = Wot + WSZ;          // [8192,1024]
    unsigned short* Km  = Q + XSZ;            // [8192,1024]
    unsigned short* Vt  = Km + XSZ;           // [1024,8192] = V^T (all batches: col m = b*2048+n)
    unsigned short* S   = Vt + XSZ;           // [4][2048,2048] (S -> P in place)
    unsigned short* Aat = xb;                 // alias: x dead after V projection
    // total: 5*XSZ + 4*WSZ + 16.7M elems = ~104 MiB

    const dim3 blk(256);

    // conversions / weight transposes
    cvt_f32_bf16 <<<dim3(8192), blk, 0, stream>>>(x, xb, (int)(XSZ / 4));
    cvt_transpose<<<dim3(32, 32), blk, 0, stream>>>(Wq, Wqt, 1024, 1024);
    cvt_transpose<<<dim3(32, 32), blk, 0, stream>>>(Wk, Wkt, 1024, 1024);
    cvt_transpose<<<dim3(32, 32), blk, 0, stream>>>(Wv, Wvt, 1024, 1024);
    cvt_transpose<<<dim3(32, 32), blk, 0, stream>>>(Wo, Wot, 1024, 1024);

    // QKV projections: [8192,1024] @ W + b
    gemm128<false, false, 0><<<dim3(64, 8, 1), blk, 0, stream>>>(
        xb, Wqt, bq, Q,  1024, 1024, 1024, 1024, 0, 0, 0, 1.f);
    gemm128<false, false, 0><<<dim3(64, 8, 1), blk, 0, stream>>>(
        xb, Wkt, bk, Km, 1024, 1024, 1024, 1024, 0, 0, 0, 1.f);
    // V projection written transposed: Vt[1024, 8192], ldc = 8192
    gemm128<false, false, 2><<<dim3(64, 8, 1), blk, 0, stream>>>(
        xb, Wvt, bv, Vt, 1024, 1024, 1024, 8192, 0, 0, 0, 1.f);

    // S = Q K^T / sqrt(D), causal blocks only (per-batch via grid.z)
    gemm128<true, false, 0><<<dim3(16, 16, 4), blk, 0, stream>>>(
        Q, Km, nullptr, S, 1024, 1024, 1024, 2048,
        2048L * 1024, 2048L * 1024, 2048L * 2048, 0.03125f);

    // causal softmax rows, in place, zero-padded to 128 boundary
    softmax_causal<<<dim3(4 * 2048), blk, 0, stream>>>(S, 2048);

    // A = P @ V  (Bt = V^T slice, row stride 8192, batch stride 2048 cols)
    gemm128<false, true, 0><<<dim3(16, 8, 4), blk, 0, stream>>>(
        S, Vt, nullptr, Aat, 2048, 2048, 8192, 1024,
        2048L * 2048, 2048, 2048L * 1024, 1.f);

    // out = A @ Wo + bo  (fp32 out)
    gemm128<false, false, 1><<<dim3(64, 8, 1), blk, 0, stream>>>(
        Aat, Wot, bo, (float*)d_out, 1024, 1024, 1024, 1024, 0, 0, 0, 1.f);
}

// Round 4
// 358.450 us; speedup vs baseline: 2.0602x; 1.1717x over previous
//
#include <hip/hip_runtime.h>
#include <hip/hip_bf16.h>

typedef __attribute__((ext_vector_type(8))) short short8;
typedef __attribute__((ext_vector_type(4))) float f32x4;

__device__ inline float b2f(unsigned short u) {
    union { unsigned int i; float f; } c; c.i = ((unsigned int)u) << 16; return c.f;
}
__device__ inline unsigned short f2b(float f) {
    __hip_bfloat16 h = __float2bfloat16(f);
    return *reinterpret_cast<unsigned short*>(&h);
}

// async global->LDS, 16 B per lane; LDS dest = wave-uniform base + lane*16
__device__ inline void gl_lds16(const unsigned short* g, unsigned short* ldsbase) {
    __builtin_amdgcn_global_load_lds(
        (const __attribute__((address_space(1))) unsigned int*)(g),
        (__attribute__((address_space(3))) unsigned int*)(ldsbase),
        16, 0, 0);
}

// fp32 -> bf16 conversion, 4 elems/thread
__global__ __launch_bounds__(256) void cvt_f32_bf16(
    const float* __restrict__ src, unsigned short* __restrict__ dst, int n4)
{
    int i = blockIdx.x * 256 + threadIdx.x;
    if (i >= n4) return;
    float4 v = ((const float4*)src)[i];
    union { unsigned short u[4]; unsigned long long ll; } p;
    p.u[0] = f2b(v.x); p.u[1] = f2b(v.y); p.u[2] = f2b(v.z); p.u[3] = f2b(v.w);
    ((unsigned long long*)dst)[i] = p.ll;
}

// fp32 [R,C] -> bf16 transposed [C,R], 32x32 LDS tiles
__global__ __launch_bounds__(256) void cvt_transpose(
    const float* __restrict__ src, unsigned short* __restrict__ dst, int R, int C)
{
    __shared__ float tile[32][33];
    const int c0 = blockIdx.x * 32, r0 = blockIdx.y * 32;
    const int tx = threadIdx.x & 31, ty = threadIdx.x >> 5;
    #pragma unroll
    for (int i = ty; i < 32; i += 8)
        tile[i][tx] = src[(long)(r0 + i) * C + c0 + tx];
    __syncthreads();
    #pragma unroll
    for (int i = ty; i < 32; i += 8)
        dst[(long)(c0 + i) * R + r0 + tx] = f2b(tile[tx][i]);
}

// ---- shared tile machinery (BK=64, two 32-k panels per barrier) ----
// As/Bs layout: panel p in [0,2), As[p][128][32]; proven m97 read pattern per panel.

#define TILE_DECLS \
    __shared__ __attribute__((aligned(16))) unsigned short As[2 * 128 * 32]; \
    __shared__ __attribute__((aligned(16))) unsigned short Bs[2 * 128 * 32]; \
    const int t = threadIdx.x, lane = t & 63, w = t >> 6; \
    const int wr = w >> 1, wc = w & 1; \
    const int lrow = lane & 15, quad = lane >> 4; \
    f32x4 acc[4][4]; \
    _Pragma("unroll") for (int i = 0; i < 4; i++) \
        _Pragma("unroll") for (int j = 0; j < 4; j++) \
            acc[i][j] = (f32x4){0.f, 0.f, 0.f, 0.f};

#define TILE_KLOOP(gA, lda, gB, ldb, Keff) \
    for (int k0 = 0; k0 < (Keff); k0 += 64) { \
        _Pragma("unroll") for (int p = 0; p < 2; p++) \
            _Pragma("unroll") for (int h = 0; h < 2; h++) { \
                gl_lds16((gA) + (long)h * 16 * (lda) + k0 + p * 32, \
                         &As[p * 4096 + (w * 32 + h * 16) * 32]); \
                gl_lds16((gB) + (long)h * 16 * (ldb) + k0 + p * 32, \
                         &Bs[p * 4096 + (w * 32 + h * 16) * 32]); \
            } \
        __syncthreads(); \
        _Pragma("unroll") for (int p = 0; p < 2; p++) { \
            short8 af[4], bfr[4]; \
            _Pragma("unroll") for (int mi = 0; mi < 4; mi++) \
                af[mi] = *(const short8*)&As[p * 4096 + (wr * 64 + mi * 16 + lrow) * 32 + quad * 8]; \
            _Pragma("unroll") for (int ni = 0; ni < 4; ni++) \
                bfr[ni] = *(const short8*)&Bs[p * 4096 + (wc * 64 + ni * 16 + lrow) * 32 + quad * 8]; \
            _Pragma("unroll") for (int mi = 0; mi < 4; mi++) \
                _Pragma("unroll") for (int ni = 0; ni < 4; ni++) \
                    acc[mi][ni] = __builtin_amdgcn_mfma_f32_16x16x32_bf16( \
                        af[mi], bfr[ni], acc[mi][ni], 0, 0, 0); \
        } \
        __syncthreads(); \
    }

// Fused QKV projection: x[8192,1024] @ {Wq,Wk,Wv} + b -> Q, K (row-major), Vt (transposed)
// grid (64, 24): bn<8 -> Q, bn<16 -> K, else -> Vt
__global__ __launch_bounds__(256) void qkv_proj(
    const unsigned short* __restrict__ A,
    const unsigned short* __restrict__ Wqt, const unsigned short* __restrict__ Wkt,
    const unsigned short* __restrict__ Wvt,
    const float* __restrict__ bq, const float* __restrict__ bk, const float* __restrict__ bv,
    unsigned short* __restrict__ Q, unsigned short* __restrict__ Km,
    unsigned short* __restrict__ Vt)
{
    const int bm = blockIdx.x, bn = blockIdx.y;
    const int r = bn >> 3, bnn = bn & 7;
    const unsigned short* Bt = (r == 0) ? Wqt : (r == 1) ? Wkt : Wvt;
    const float* bias = (r == 0) ? bq : (r == 1) ? bk : bv;
    const int m0 = bm * 128, n0 = bnn * 128;

    TILE_DECLS

    const unsigned short* gA = A  + (long)(m0 + w * 32 + (lane >> 2)) * 1024 + (lane & 3) * 8;
    const unsigned short* gB = Bt + (long)(n0 + w * 32 + (lane >> 2)) * 1024 + (lane & 3) * 8;
    TILE_KLOOP(gA, 1024, gB, 1024, 1024)

    #pragma unroll
    for (int mi = 0; mi < 4; mi++) {
        const int m = m0 + wr * 64 + mi * 16 + quad * 4;
        #pragma unroll
        for (int ni = 0; ni < 4; ni++) {
            const int n = n0 + wc * 64 + ni * 16 + lrow;
            const float bvl = bias[n];
            if (r < 2) {
                unsigned short* out = (r == 0) ? Q : Km;
                #pragma unroll
                for (int rg = 0; rg < 4; rg++)
                    out[(long)(m + rg) * 1024 + n] = f2b(acc[mi][ni][rg] + bvl);
            } else {
                #pragma unroll
                for (int rg = 0; rg < 4; rg++)
                    Vt[(long)n * 8192 + m + rg] = f2b(acc[mi][ni][rg] + bvl);
            }
        }
    }
}

// C = scale * A[M,K] @ Bt^T + bias
//  TRI    : triangular grid — blockIdx.x = linear lower-tri index, blockIdx.y = batch
//  KCAUSAL: K-loop capped at (bm+1)*128
//  OMODE 0: C bf16 row-major; 1: C fp32 row-major
template<bool TRI, bool KCAUSAL, int OMODE>
__global__ __launch_bounds__(256) void gemm128(
    const unsigned short* __restrict__ A, const unsigned short* __restrict__ Bt,
    const float* __restrict__ bias, void* __restrict__ Cv,
    int K, int lda, int ldb, int ldc, long sA, long sB, long sC, float scale)
{
    int bm, bn, bz;
    if (TRI) {
        const int q = blockIdx.x;
        bm = (int)((sqrtf(8.f * q + 1.f) - 1.f) * 0.5f);
        while ((bm + 1) * (bm + 2) / 2 <= q) bm++;
        while (bm * (bm + 1) / 2 > q) bm--;
        bn = q - bm * (bm + 1) / 2;
        bz = blockIdx.y;
    } else {
        bm = blockIdx.x; bn = blockIdx.y; bz = blockIdx.z;
    }
    A  += (long)bz * sA;
    Bt += (long)bz * sB;
    const int m0 = bm * 128, n0 = bn * 128;

    TILE_DECLS

    const int Keff = KCAUSAL ? ((bm + 1) * 128 < K ? (bm + 1) * 128 : K) : K;
    const unsigned short* gA = A  + (long)(m0 + w * 32 + (lane >> 2)) * lda + (lane & 3) * 8;
    const unsigned short* gB = Bt + (long)(n0 + w * 32 + (lane >> 2)) * ldb + (lane & 3) * 8;
    TILE_KLOOP(gA, lda, gB, ldb, Keff)

    #pragma unroll
    for (int mi = 0; mi < 4; mi++) {
        const int m = m0 + wr * 64 + mi * 16 + quad * 4;
        #pragma unroll
        for (int ni = 0; ni < 4; ni++) {
            const int n = n0 + wc * 64 + ni * 16 + lrow;
            const float bvl = bias ? bias[n] : 0.f;
            #pragma unroll
            for (int rg = 0; rg < 4; rg++) {
                const float val = acc[mi][ni][rg] * scale + bvl;
                if (OMODE == 1)
                    ((float*)Cv)[(long)bz * sC + (long)(m + rg) * ldc + n] = val;
                else
                    ((unsigned short*)Cv)[(long)bz * sC + (long)(m + rg) * ldc + n] = f2b(val);
            }
        }
    }
}

// In-place causal row softmax over S (bf16); zero-fills [i+1, 128-padded).
__global__ __launch_bounds__(256) void softmax_causal(unsigned short* S, int Nseq)
{
    const long row = blockIdx.x;
    const int i = (int)(row % Nseq);
    unsigned short* base = S + row * (long)Nseq;
    const int len = i + 1;
    const int t = threadIdx.x;

    __shared__ float smax[4], ssum[4];

    float lmax = -3.0e38f;
    for (int j = t; j < len; j += 256) lmax = fmaxf(lmax, b2f(base[j]));
    #pragma unroll
    for (int off = 32; off > 0; off >>= 1) lmax = fmaxf(lmax, __shfl_xor(lmax, off, 64));
    if ((t & 63) == 0) smax[t >> 6] = lmax;
    __syncthreads();
    const float gmax = fmaxf(fmaxf(smax[0], smax[1]), fmaxf(smax[2], smax[3]));

    float lsum = 0.f;
    for (int j = t; j < len; j += 256) lsum += __expf(b2f(base[j]) - gmax);
    #pragma unroll
    for (int off = 32; off > 0; off >>= 1) lsum += __shfl_xor(lsum, off, 64);
    if ((t & 63) == 0) ssum[t >> 6] = lsum;
    __syncthreads();
    const float inv = 1.0f / (ssum[0] + ssum[1] + ssum[2] + ssum[3]);

    const int padded = ((i >> 7) + 1) << 7;
    for (int j = t; j < padded; j += 256) {
        const float v = (j < len) ? __expf(b2f(base[j]) - gmax) * inv : 0.f;
        base[j] = f2b(v);
    }
}

extern "C" void kernel_launch(void* const* d_in, const int* in_sizes, int n_in,
                              void* d_out, int out_size, void* d_ws, size_t ws_size,
                              hipStream_t stream)
{
    // inputs (fp32): x, mask(ignored - known causal), Wq, bq, Wk, bk, Wv, bv, Wo, bo
    const float* x  = (const float*)d_in[0];
    const float* Wq = (const float*)d_in[2];
    const float* bq = (const float*)d_in[3];
    const float* Wk = (const float*)d_in[4];
    const float* bk = (const float*)d_in[5];
    const float* Wv = (const float*)d_in[6];
    const float* bv = (const float*)d_in[7];
    const float* Wo = (const float*)d_in[8];
    const float* bo = (const float*)d_in[9];

    unsigned short* ws = (unsigned short*)d_ws;
    const long XSZ = 8192L * 1024;
    const long WSZ = 1024L * 1024;
    unsigned short* xb  = ws;                 // [8192,1024] bf16 (aliased by attn-out later)
    unsigned short* Wqt = ws + XSZ;           // [1024,1024] = Wq^T
    unsigned short* Wkt = Wqt + WSZ;
    unsigned short* Wvt = Wkt + WSZ;
    unsigned short* Wot = Wvt + WSZ;
    unsigned short* Q   = Wot + WSZ;          // [8192,1024]
    unsigned short* Km  = Q + XSZ;            // [8192,1024]
    unsigned short* Vt  = Km + XSZ;           // [1024,8192] = V^T (col m = b*2048+n)
    unsigned short* S   = Vt + XSZ;           // [4][2048,2048] (S -> P in place)
    unsigned short* Aat = xb;                 // alias: x dead after QKV projection

    const dim3 blk(256);

    cvt_f32_bf16 <<<dim3(8192), blk, 0, stream>>>(x, xb, (int)(XSZ / 4));
    cvt_transpose<<<dim3(32, 32), blk, 0, stream>>>(Wq, Wqt, 1024, 1024);
    cvt_transpose<<<dim3(32, 32), blk, 0, stream>>>(Wk, Wkt, 1024, 1024);
    cvt_transpose<<<dim3(32, 32), blk, 0, stream>>>(Wv, Wvt, 1024, 1024);
    cvt_transpose<<<dim3(32, 32), blk, 0, stream>>>(Wo, Wot, 1024, 1024);

    // fused QKV projection, 1536 blocks
    qkv_proj<<<dim3(64, 24), blk, 0, stream>>>(
        xb, Wqt, Wkt, Wvt, bq, bk, bv, Q, Km, Vt);

    // S = Q K^T / sqrt(D), triangular grid (136 active blocks x 4 batches)
    gemm128<true, false, 0><<<dim3(136, 4), blk, 0, stream>>>(
        Q, Km, nullptr, S, 1024, 1024, 1024, 2048,
        2048L * 1024, 2048L * 1024, 2048L * 2048, 0.03125f);

    softmax_causal<<<dim3(4 * 2048), blk, 0, stream>>>(S, 2048);

    // A = P @ V  (Bt = V^T slice, row stride 8192, batch offset 2048 cols)
    gemm128<false, true, 0><<<dim3(16, 8, 4), blk, 0, stream>>>(
        S, Vt, nullptr, Aat, 2048, 2048, 8192, 1024,
        2048L * 2048, 2048, 2048L * 1024, 1.f);

    // out = A @ Wo + bo (fp32)
    gemm128<false, false, 1><<<dim3(64, 8, 1), blk, 0, stream>>>(
        Aat, Wot, bo, (float*)d_out, 1024, 1024, 1024, 1024, 0, 0, 0, 1.f);
}